// Round 3
// 1160.898 us; speedup vs baseline: 1.0205x; 1.0205x over previous
//
#include <hip/hip_runtime.h>

// InteractionArch via per-sample MFMA Gram matrix.
// B=65536 samples; X = 27x128 fp32 per sample (1 dense row + 26 sparse rows).
// C = X·X^T computed as one padded 32x32 tile per WAVE using
// v_mfma_f32_32x32x16_bf16, with fp32 precision recovered by the
// hi/lo bf16 split: C ≈ hi·hi^T + hi·lo^T + lo·hi^T  (error ~2^-17 rel,
// absmax ~1e-3 vs the 0.25 test threshold).
//
// Fragment trick: for Gram, A-frag and B-frag have IDENTICAL per-lane
// contents (lane l holds X[l&31][8*(l>>5)+j], j=0..7 — A is row-indexed,
// B is col-indexed with the same k distribution), so one register vector
// feeds both operands. Numerically robust: any common k-permutation is
// invariant under the sum, and a C/D transpose is harmless (C symmetric).
//
// bf16 handled as short8 + bit-level RNE conversion (the compile-verified
// gfx950 pattern from the m90-m103 modules) — no __bf16 language type.

constexpr int F      = 27;
constexpr int NPAIRS = F * (F - 1) / 2;   // 351
constexpr int D      = 128;
constexpr int SPB    = 4;                  // samples per 256-thread block (1 per wave)

typedef __attribute__((ext_vector_type(8)))  short bf16x8;   // 8 bf16 in 4 VGPRs
typedef __attribute__((ext_vector_type(16))) float f32x16;   // 32x32 C/D fragment

__device__ __forceinline__ unsigned short f32_to_bf16_rne(float x) {
    unsigned u = __float_as_uint(x);
    unsigned r = u + 0x7fffu + ((u >> 16) & 1u);   // round-to-nearest-even
    return (unsigned short)(r >> 16);
}
__device__ __forceinline__ float bf16_to_f32(unsigned short h) {
    return __uint_as_float((unsigned)h << 16);
}

__global__ __launch_bounds__(256)
void interact_mfma(const float* __restrict__ dense,
                   const float* __restrict__ sparse,
                   float* __restrict__ out, int B) {
    const int tid = threadIdx.x;
    const int l   = tid & 63;            // lane in wave
    const int r   = l & 31;              // Gram row/col owned by this lane
    const int h   = l >> 5;              // k-half selector
    const long b  = (long)blockIdx.x * SPB + (tid >> 6);
    if (b >= B) return;

    const bool valid = (r < F);
    // invalid lanes (r=27..31) re-read the dense row (same cache lines as
    // lane 0 -> zero extra HBM traffic) and are zeroed before conversion.
    const float* rowp = (r == 0 || !valid)
        ? dense  + b * (long)D
        : sparse + (b * 26L + (r - 1)) * (long)D;

    // ---- load this lane's k-half of its row: 64 floats = 16x float4 ----
    float4 v[16];
    #pragma unroll
    for (int t = 0; t < 8; ++t) {
        const float* p = rowp + t * 16 + h * 8;   // 32B-aligned
        v[2 * t]     = *(const float4*)p;
        v[2 * t + 1] = *(const float4*)(p + 4);
    }

    f32x16 acc = {};

    #pragma unroll
    for (int t = 0; t < 8; ++t) {
        float xs[8];
        #pragma unroll
        for (int j = 0; j < 4; ++j) {
            xs[j]     = (&v[2 * t].x)[j];
            xs[j + 4] = (&v[2 * t + 1].x)[j];
        }
        bf16x8 hi, lo;
        #pragma unroll
        for (int j = 0; j < 8; ++j) {
            float x = valid ? xs[j] : 0.0f;
            unsigned short hb = f32_to_bf16_rne(x);
            float lf = x - bf16_to_f32(hb);        // exact residual
            hi[j] = (short)hb;
            lo[j] = (short)f32_to_bf16_rne(lf);
        }
        // same registers serve as A (rows) and B (cols): C = X·X^T
        acc = __builtin_amdgcn_mfma_f32_32x32x16_bf16(hi, hi, acc, 0, 0, 0);
        acc = __builtin_amdgcn_mfma_f32_32x32x16_bf16(hi, lo, acc, 0, 0, 0);
        acc = __builtin_amdgcn_mfma_f32_32x32x16_bf16(lo, hi, acc, 0, 0, 0);
    }

    // ---- epilogue: strict upper triangle, row-major packed ----
    // C/D layout (m74/m101, HW-verified): col = lane&31,
    //                                     row = (reg&3) + 8*(reg>>2) + 4*(lane>>5)
    if (!valid) return;
    float* ob = out + b * (long)NPAIRS;
    const int j = r;                       // column owned by this lane
    #pragma unroll
    for (int e = 0; e < 16; ++e) {
        int i = (e & 3) + 8 * (e >> 2) + 4 * h;
        if (i < j) {                       // i<j<=26 -> offset in [0,351)
            int o = i * (2 * F - i - 1) / 2 + (j - i - 1);
            ob[o] = acc[e];
        }
    }
}

extern "C" void kernel_launch(void* const* d_in, const int* in_sizes, int n_in,
                              void* d_out, int out_size, void* d_ws, size_t ws_size,
                              hipStream_t stream) {
    const float* dense  = (const float*)d_in[0];
    const float* sparse = (const float*)d_in[1];
    float* out = (float*)d_out;
    const int B = in_sizes[0] / D;                 // 65536
    const int grid = (B + SPB - 1) / SPB;          // 16384
    interact_mfma<<<grid, 256, 0, stream>>>(dense, sparse, out, B);
}